// Round 10
// baseline (640.556 us; speedup 1.0000x reference)
//
#include <hip/hip_runtime.h>

#define HW 262144   // 512*512
#define EPSF 1e-5f

typedef __attribute__((ext_vector_type(8))) short bf16x8;
typedef __attribute__((ext_vector_type(4))) float f32x4;

__device__ __forceinline__ unsigned short f2bf(float f) {
    unsigned u = __builtin_bit_cast(unsigned, f);
    return (unsigned short)((u + 0x7FFFu + ((u >> 16) & 1u)) >> 16);  // RNE
}

typedef __attribute__((address_space(3))) unsigned lds_u32_t;
typedef __attribute__((address_space(1))) const unsigned glb_u32_t;
__device__ __forceinline__ void dma16(const void* gsrc, void* ldst) {
    __builtin_amdgcn_global_load_lds((glb_u32_t*)gsrc, (lds_u32_t*)ldst, 16, 0, 0);
}

// ws layout (bytes):
//   w2ws @ 0        : frag-major [8ch][2coh][9tap][4g][128co][8hc] ushort
//                     = 1,179,648 (slot 1,212,416)
//   w1ws @ 1212416  : [256hc][72ci] ushort (BN1-folded) = 36,864
//   t1ws @ 1249280  : float[256]
//   s2ws @ 1250304  : float[256]
//   t2ws @ 1251328  : float[256]
//   wdws @ 1252352  : [256co][72ci] ushort = 36,864
//   mskw @ 1289216  : byte[512]
#define W2WS_OFF 0
#define W1WS_OFF 1212416
#define T1WS_OFF 1249280
#define S2WS_OFF 1250304
#define T2WS_OFF 1251328
#define WDWS_OFF 1252352
#define MSKWS_OFF 1289216

// ---------------------------------------------------------------------------
__global__ __launch_bounds__(512) void kmask(const int* __restrict__ indices,
                                             int nB, char* __restrict__ ws) {
    unsigned char* mb = (unsigned char*)(ws + MSKWS_OFF);
    const int t = threadIdx.x;
    if (t < 512) mb[t] = 0;
    __syncthreads();
    if (t < nB) {
        int bn = indices[t*3+0], gh = indices[t*3+1], gw = indices[t*3+2];
        if ((unsigned)bn < 2u && (unsigned)gh < 16u && (unsigned)gw < 16u)
            mb[bn*256 + gh*16 + gw] = 1;
    }
}

// ---------------------------------------------------------------------------
__global__ __launch_bounds__(256) void kprep(
    const float* __restrict__ w1, const float* __restrict__ b1,
    const float* __restrict__ g1, const float* __restrict__ be1,
    const float* __restrict__ m1, const float* __restrict__ v1,
    const float* __restrict__ w2, const float* __restrict__ b2,
    const float* __restrict__ g2, const float* __restrict__ be2,
    const float* __restrict__ m2, const float* __restrict__ v2,
    const float* __restrict__ wd,
    char* __restrict__ ws)
{
    unsigned short* w2ws = (unsigned short*)(ws + W2WS_OFF);
    unsigned short* w1ws = (unsigned short*)(ws + W1WS_OFF);
    unsigned short* wdws = (unsigned short*)(ws + WDWS_OFF);
    float* t1ws = (float*)(ws + T1WS_OFF);
    float* s2ws = (float*)(ws + S2WS_OFF);
    float* t2ws = (float*)(ws + T2WS_OFF);

    const int bid = blockIdx.x, t = threadIdx.x;
    if (bid < 2304) {                      // w2 -> frag-major, 589,824 elems
        int e_lin = bid*256 + t;
        int e  = e_lin & 7;
        int co = (e_lin >> 3) & 127;
        int g  = (e_lin >> 10) & 3;
        int r  = e_lin >> 12;              // 0..143
        int tap = r % 9;
        int q  = r / 9;                    // 0..15
        int coh = q & 1, ch = q >> 1;
        int hc = ch*32 + g*8 + e;
        int co_g = coh*128 + co;
        w2ws[e_lin] = f2bf(w2[(size_t)co_g*2304 + (size_t)hc*9 + tap]);
    } else if (bid < 2368) {               // w1 folded
        int e = (bid-2304)*256 + t;
        int hc = e >> 6, ci = e & 63;
        float s1 = g1[hc] * rsqrtf(v1[hc] + EPSF);
        w1ws[hc*72 + ci] = f2bf(w1[hc*64+ci] * s1);
    } else if (bid < 2432) {               // wd
        int e = (bid-2368)*256 + t;
        int co = e >> 6, ci = e & 63;
        wdws[co*72 + ci] = f2bf(wd[co*64 + ci]);
    } else {
        if (t < 256) {
            float s1 = g1[t] * rsqrtf(v1[t] + EPSF);
            t1ws[t] = (b1[t]-m1[t])*s1 + be1[t];
            float s2 = g2[t] * rsqrtf(v2[t] + EPSF);
            s2ws[t] = s2;
            t2ws[t] = (b2[t]-m2[t])*s2 + be2[t];
        }
    }
}

// ---------------------------------------------------------------------------
// k1_mfma: unchanged (verified)
// ---------------------------------------------------------------------------
__global__ __launch_bounds__(256, 2) void k1_mfma(
    const float* __restrict__ x,
    const float* __restrict__ bd, const char* __restrict__ ws,
    const int* __restrict__ bstride, const int* __restrict__ boff,
    float* __restrict__ y)
{
    extern __shared__ char smem[];
    unsigned short* xT  = (unsigned short*)smem;            // [256][72]
    unsigned short* wdS = (unsigned short*)(smem + 36864);  // [256][72]
    float*          bdS = (float*)(smem + 73728);           // [256]

    const int t = threadIdx.x, lane = t & 63, w = t >> 6;
    const int m = lane & 15, g = lane >> 4;
    const int bid = blockIdx.x;
    const int n   = bid >> 10;
    const int row = (bid >> 1) & 511;
    const int c0  = (bid & 1) * 256;

    #pragma unroll
    for (int i = 0; i < 9; ++i)
        dma16((const char*)ws + WDWS_OFF + (t + i*256)*16,
              (char*)wdS + (t + i*256)*16);
    if (t < 64) dma16((const char*)bd + t*16, (char*)bdS + t*16);

    const size_t xbase = (size_t)n*64*HW + (size_t)row*512 + c0;
    #pragma unroll 4
    for (int jc = 0; jc < 16; ++jc) {
        int ci = w + 4*jc;
        float4 xv = *(const float4*)&x[xbase + (size_t)ci*HW + lane*4];
        xT[(lane*4+0)*72 + ci] = f2bf(xv.x);
        xT[(lane*4+1)*72 + ci] = f2bf(xv.y);
        xT[(lane*4+2)*72 + ci] = f2bf(xv.z);
        xT[(lane*4+3)*72 + ci] = f2bf(xv.w);
    }

    const int stride = bstride[0], off = boff[0];
    const bool safe = (stride == 32) && (off == 0);
    unsigned long long mv = 0;
    if (safe) {
        const unsigned char* mb = (const unsigned char*)(ws + MSKWS_OFF);
        mv = *(const unsigned long long*)&mb[n*256 + (row>>5)*16 + (bid&1)*8];
    }

    __syncthreads();

    bf16x8 bF[2][4];
    #pragma unroll
    for (int pxf = 0; pxf < 4; ++pxf)
        #pragma unroll
        for (int kk = 0; kk < 2; ++kk)
            bF[kk][pxf] = *(const bf16x8*)&xT[(w*64 + pxf*16 + m)*72 + kk*32 + g*8];

    const size_t ybase = (size_t)(n*256)*HW + (size_t)row*512 + c0;
    #pragma unroll 1
    for (int cof = 0; cof < 16; ++cof) {
        bf16x8 a0  = *(const bf16x8*)&wdS[(cof*16+m)*72 +      g*8];
        bf16x8 a1w = *(const bf16x8*)&wdS[(cof*16+m)*72 + 32 + g*8];
        f32x4 ac[4];
        #pragma unroll
        for (int pxf = 0; pxf < 4; ++pxf) {
            ac[pxf] = (f32x4){0.f,0.f,0.f,0.f};
            ac[pxf] = __builtin_amdgcn_mfma_f32_16x16x32_bf16(a0,  bF[0][pxf], ac[pxf], 0, 0, 0);
            ac[pxf] = __builtin_amdgcn_mfma_f32_16x16x32_bf16(a1w, bF[1][pxf], ac[pxf], 0, 0, 0);
        }
        #pragma unroll
        for (int pxf = 0; pxf < 4; ++pxf) {
            const int pxg = w*4 + pxf;
            const bool skip = safe && (((mv >> ((pxg>>1)*8)) & 0xffull) != 0ull);
            if (!skip) {
                #pragma unroll
                for (int j = 0; j < 4; ++j) {
                    const int co = cof*16 + g*4 + j;
                    y[ybase + (size_t)co*HW + pxg*16 + m] = ac[pxf][j] + bdS[co];
                }
            }
        }
    }
}

// ---------------------------------------------------------------------------
// k2_fused, round 10: 2 WG/CU restructure.
//  * WG = (block, pz stripe, co-half of 128). grid 2048, 512 thr.
//  * w2 A-frags: DIRECT global->VGPR from frag-major w2ws (L2-resident,
//    quarter-wave reads 256B contiguous). No w2 LDS, no w2 DMA drains.
//  * LDS = xT[340][72] + w1s[32][72] + hS[340][40] = 80,768 B -> 2 WG/CU.
//  * BN tables read from global (L2-hot) instead of LDS.
//  * 2 barriers per ch.  conv1 redundant per co-half (+4% MFMA, cheap).
// ---------------------------------------------------------------------------
__global__ __launch_bounds__(512, 4) void k2_fused(
    const float* __restrict__ x, const int* __restrict__ indices,
    const char* __restrict__ ws,
    const int* __restrict__ bstride, const int* __restrict__ boff,
    float* __restrict__ y)
{
    extern __shared__ char smem[];
    unsigned short* xT  = (unsigned short*)smem;            // [340][72] 48,960B
    unsigned short* w1s = (unsigned short*)(smem + 48960);  // [32][72]   4,608B
    unsigned short* hS  = (unsigned short*)(smem + 53568);  // [340][40] 27,200B
    // total 80,768 B  -> 2 WG/CU (163,840/2 = 81,920)

    const unsigned short* w2g  = (const unsigned short*)(ws + W2WS_OFF);
    const unsigned short* w1ws = (const unsigned short*)(ws + W1WS_OFF);
    const float* t1g = (const float*)(ws + T1WS_OFF);
    const float* s2g = (const float*)(ws + S2WS_OFF);
    const float* t2g = (const float*)(ws + T2WS_OFF);

    const int t    = threadIdx.x;
    const int lane = t & 63;
    const int w    = t >> 6;
    const int m    = lane & 15;
    const int g    = lane >> 4;
    const int cog  = w >> 2;        // 0..1  co-group of 64 within this half
    const int ph   = w & 3;         // 0..3  row-pair

    const int bid = blockIdx.x;
    const int blk = bid >> 3, pz = (bid >> 1) & 3, coh = bid & 1;
    const int bn = indices[blk*3+0], gr = indices[blk*3+1], gc = indices[blk*3+2];
    const int stride = bstride[0], off = boff[0];
    const int row0 = gr*stride + off, col0 = gc*stride + off;

    // per-lane constant part of the A-frag offset (ushort units)
    const int alo = g*1024 + (cog*64 + m)*8;

    // ---- prologue: w1s(0) DMA + xT staging ----
    if (t < 288) dma16((const char*)w1ws + t*16, (char*)w1s + t*16);
    {
        const int half = lane >> 5, cc = lane & 31;
        for (int pb = w*80; pb < w*80 + 80; pb += 2) {
            int pi = pb + half;
            int r = pi >> 6, ci = pi & 63;
            int br = pz*8 + r - 1;
            if ((unsigned)br < 32u) {
                float xv = x[(size_t)bn*64*HW + (size_t)ci*HW
                             + (size_t)(row0+br)*512 + (col0+cc)];
                xT[(r*34 + cc + 1)*72 + ci] = f2bf(xv);
            }
        }
    }

    f32x4 acc[4][4];    // [cof][pxf = pr*2+chf]
    #pragma unroll
    for (int a = 0; a < 4; ++a)
        #pragma unroll
        for (int b = 0; b < 4; ++b) acc[a][b] = (f32x4){0.f,0.f,0.f,0.f};

    __syncthreads();   // xT visible, w1s(0) drained

    #pragma unroll 1
    for (int ch = 0; ch < 8; ++ch) {
        // ---- conv1 MFMA (xT, w1s) + BN1 bias from global ----
        float4 t1v0 = *(const float4*)&t1g[ch*32      + g*4];
        float4 t1v1 = *(const float4*)&t1g[ch*32 + 16 + g*4];
        f32x4 a1[3][2];
        #pragma unroll
        for (int i = 0; i < 3; ++i) {
            a1[i][0] = (f32x4){0.f,0.f,0.f,0.f};
            a1[i][1] = (f32x4){0.f,0.f,0.f,0.f};
            const int tile = w*3 + i;
            if (tile < 22) {
                #pragma unroll
                for (int kk = 0; kk < 2; ++kk) {
                    bf16x8 bF1 = *(const bf16x8*)&xT[(tile*16+m)*72 + kk*32 + g*8];
                    #pragma unroll
                    for (int hct = 0; hct < 2; ++hct) {
                        bf16x8 aF1 = *(const bf16x8*)&w1s[(hct*16+m)*72 + kk*32 + g*8];
                        a1[i][hct] = __builtin_amdgcn_mfma_f32_16x16x32_bf16(
                                         aF1, bF1, a1[i][hct], 0, 0, 0);
                    }
                }
            }
        }
        // ---- h write: bias + relu + border mask (gate p<340) ----
        #pragma unroll
        for (int i = 0; i < 3; ++i) {
            const int tile = w*3 + i;
            if (tile < 22) {
                int p = tile*16 + m;
                if (p < 340) {
                    int r = p / 34, c = p - r*34;
                    int br = pz*8 + r - 1;
                    bool valid = (c >= 1) && (c <= 32) && ((unsigned)br < 32u);
                    #pragma unroll
                    for (int hct = 0; hct < 2; ++hct) {
                        const float4 tv4 = hct ? t1v1 : t1v0;
                        unsigned short hv[4];
                        #pragma unroll
                        for (int j = 0; j < 4; ++j) {
                            float hf = fmaxf(a1[i][hct][j] +
                                             ((const float*)&tv4)[j], 0.f);
                            hv[j] = valid ? f2bf(hf) : (unsigned short)0;
                        }
                        unsigned lo = (unsigned)hv[0] | ((unsigned)hv[1] << 16);
                        unsigned hi = (unsigned)hv[2] | ((unsigned)hv[3] << 16);
                        *(uint2*)&hS[p*40 + hct*16 + g*4] = make_uint2(lo, hi);
                    }
                }
            }
        }
        __syncthreads();   // hS(ch) visible

        if (ch < 7 && t < 288)
            dma16((const char*)w1ws + (ch+1)*4608 + t*16, (char*)w1s + t*16);

        // ---- conv2: A from global (L2), B from hS ----
        __builtin_amdgcn_s_setprio(1);
        #pragma unroll
        for (int dx = 0; dx < 3; ++dx) {
            bf16x8 bFr[2][4];
            #pragma unroll
            for (int chf = 0; chf < 2; ++chf)
                #pragma unroll
                for (int ro = 0; ro < 4; ++ro)
                    bFr[chf][ro] = *(const bf16x8*)
                        &hS[((ph*2+ro)*34 + chf*16 + m + dx)*40 + g*8];
            #pragma unroll
            for (int dy = 0; dy < 3; ++dy) {
                const int abase = ((ch*2 + coh)*9 + dy*3 + dx) * 4096;
                bf16x8 aF[4];
                #pragma unroll
                for (int cof = 0; cof < 4; ++cof)
                    aF[cof] = *(const bf16x8*)&w2g[abase + alo + cof*128];
                #pragma unroll
                for (int chf = 0; chf < 2; ++chf)
                    #pragma unroll
                    for (int pr = 0; pr < 2; ++pr)
                        #pragma unroll
                        for (int cof = 0; cof < 4; ++cof)
                            acc[cof][pr*2+chf] =
                                __builtin_amdgcn_mfma_f32_16x16x32_bf16(
                                    aF[cof], bFr[chf][pr+dy],
                                    acc[cof][pr*2+chf], 0, 0, 0);
            }
        }
        __builtin_amdgcn_s_setprio(0);
        __syncthreads();   // hS readers done; w1s(ch+1) drained
    }

    // ---- epilogue: BN2 + relu + scatter (tables from global, L2-hot) ----
    const size_t yblk = (size_t)bn*256*HW;
    const int rbase = row0 + pz*8 + ph*2;
    #pragma unroll
    for (int cof = 0; cof < 4; ++cof) {
        const int co4 = coh*128 + cog*64 + cof*16 + g*4;
        float4 s2v = *(const float4*)&s2g[co4];
        float4 t2v = *(const float4*)&t2g[co4];
        #pragma unroll
        for (int j = 0; j < 4; ++j) {
            const int co = co4 + j;
            const float s2 = ((const float*)&s2v)[j];
            const float t2 = ((const float*)&t2v)[j];
            #pragma unroll
            for (int pxf = 0; pxf < 4; ++pxf) {
                const int rr = rbase + (pxf>>1);
                const int cc2 = col0 + (pxf&1)*16 + m;
                y[yblk + (size_t)co*HW + (size_t)rr*512 + cc2] =
                    fmaxf(fmaf(acc[cof][pxf][j], s2, t2), 0.f);
            }
        }
    }
}

// ---------------------------------------------------------------------------
extern "C" void kernel_launch(void* const* d_in, const int* in_sizes, int n_in,
                              void* d_out, int out_size, void* d_ws, size_t ws_size,
                              hipStream_t stream) {
    const float* x       = (const float*)d_in[0];
    const int*   indices = (const int*)  d_in[2];
    const float* w1  = (const float*)d_in[3];
    const float* b1  = (const float*)d_in[4];
    const float* g1  = (const float*)d_in[5];
    const float* be1 = (const float*)d_in[6];
    const float* m1  = (const float*)d_in[7];
    const float* v1  = (const float*)d_in[8];
    const float* w2  = (const float*)d_in[9];
    const float* b2  = (const float*)d_in[10];
    const float* g2  = (const float*)d_in[11];
    const float* be2 = (const float*)d_in[12];
    const float* m2  = (const float*)d_in[13];
    const float* v2  = (const float*)d_in[14];
    const float* wd  = (const float*)d_in[21];
    const float* bd  = (const float*)d_in[22];
    const int* bstride = (const int*)d_in[24];
    const int* boff    = (const int*)d_in[25];
    float* y = (float*)d_out;
    char* ws = (char*)d_ws;

    const int nB = in_sizes[2] / 3;   // 256 blocks

    hipLaunchKernelGGL(kmask, dim3(1), dim3(512), 0, stream, indices, nB, ws);
    hipLaunchKernelGGL(kprep, dim3(2433), dim3(256), 0, stream,
                       w1, b1, g1, be1, m1, v1, w2, b2, g2, be2, m2, v2, wd, ws);
    hipLaunchKernelGGL(k1_mfma, dim3(2048), dim3(256), 74752, stream,
                       x, bd, ws, bstride, boff, y);
    hipLaunchKernelGGL(k2_fused, dim3(nB * 8), dim3(512), 80768, stream,
                       x, indices, ws, bstride, boff, y);
}

// Round 11
// 564.983 us; speedup vs baseline: 1.1338x; 1.1338x over previous
//
#include <hip/hip_runtime.h>

#define HW 262144   // 512*512
#define EPSF 1e-5f

typedef __attribute__((ext_vector_type(8))) short bf16x8;
typedef __attribute__((ext_vector_type(4))) float f32x4;

__device__ __forceinline__ unsigned short f2bf(float f) {
    unsigned u = __builtin_bit_cast(unsigned, f);
    return (unsigned short)((u + 0x7FFFu + ((u >> 16) & 1u)) >> 16);  // RNE
}

typedef __attribute__((address_space(3))) unsigned lds_u32_t;
typedef __attribute__((address_space(1))) const unsigned glb_u32_t;
__device__ __forceinline__ void dma16(const void* gsrc, void* ldst) {
    __builtin_amdgcn_global_load_lds((glb_u32_t*)gsrc, (lds_u32_t*)ldst, 16, 0, 0);
}

// ws layout (bytes):
//   w2ws @ 0        : frag-major [8ch][2coh][9tap][4g][128co][8hc] ushort
//                     = 1,179,648 (slot 1,212,416)
//   w1ws @ 1212416  : [256hc][72ci] ushort (BN1-folded) = 36,864
//   t1ws @ 1249280  : float[256]
//   s2ws @ 1250304  : float[256]
//   t2ws @ 1251328  : float[256]
//   wdws @ 1252352  : [256co][72ci] ushort = 36,864
//   mskw @ 1289216  : byte[512]
#define W2WS_OFF 0
#define W1WS_OFF 1212416
#define T1WS_OFF 1249280
#define S2WS_OFF 1250304
#define T2WS_OFF 1251328
#define WDWS_OFF 1252352
#define MSKWS_OFF 1289216

// ---------------------------------------------------------------------------
__global__ __launch_bounds__(512) void kmask(const int* __restrict__ indices,
                                             int nB, char* __restrict__ ws) {
    unsigned char* mb = (unsigned char*)(ws + MSKWS_OFF);
    const int t = threadIdx.x;
    if (t < 512) mb[t] = 0;
    __syncthreads();
    if (t < nB) {
        int bn = indices[t*3+0], gh = indices[t*3+1], gw = indices[t*3+2];
        if ((unsigned)bn < 2u && (unsigned)gh < 16u && (unsigned)gw < 16u)
            mb[bn*256 + gh*16 + gw] = 1;
    }
}

// ---------------------------------------------------------------------------
__global__ __launch_bounds__(256) void kprep(
    const float* __restrict__ w1, const float* __restrict__ b1,
    const float* __restrict__ g1, const float* __restrict__ be1,
    const float* __restrict__ m1, const float* __restrict__ v1,
    const float* __restrict__ w2, const float* __restrict__ b2,
    const float* __restrict__ g2, const float* __restrict__ be2,
    const float* __restrict__ m2, const float* __restrict__ v2,
    const float* __restrict__ wd,
    char* __restrict__ ws)
{
    unsigned short* w2ws = (unsigned short*)(ws + W2WS_OFF);
    unsigned short* w1ws = (unsigned short*)(ws + W1WS_OFF);
    unsigned short* wdws = (unsigned short*)(ws + WDWS_OFF);
    float* t1ws = (float*)(ws + T1WS_OFF);
    float* s2ws = (float*)(ws + S2WS_OFF);
    float* t2ws = (float*)(ws + T2WS_OFF);

    const int bid = blockIdx.x, t = threadIdx.x;
    if (bid < 2304) {                      // w2 -> frag-major, 589,824 elems
        int e_lin = bid*256 + t;
        int e  = e_lin & 7;
        int co = (e_lin >> 3) & 127;
        int g  = (e_lin >> 10) & 3;
        int r  = e_lin >> 12;              // 0..143
        int tap = r % 9;
        int q  = r / 9;                    // 0..15
        int coh = q & 1, ch = q >> 1;
        int hc = ch*32 + g*8 + e;
        int co_g = coh*128 + co;
        w2ws[e_lin] = f2bf(w2[(size_t)co_g*2304 + (size_t)hc*9 + tap]);
    } else if (bid < 2368) {               // w1 folded
        int e = (bid-2304)*256 + t;
        int hc = e >> 6, ci = e & 63;
        float s1 = g1[hc] * rsqrtf(v1[hc] + EPSF);
        w1ws[hc*72 + ci] = f2bf(w1[hc*64+ci] * s1);
    } else if (bid < 2432) {               // wd
        int e = (bid-2368)*256 + t;
        int co = e >> 6, ci = e & 63;
        wdws[co*72 + ci] = f2bf(wd[co*64 + ci]);
    } else {
        if (t < 256) {
            float s1 = g1[t] * rsqrtf(v1[t] + EPSF);
            t1ws[t] = (b1[t]-m1[t])*s1 + be1[t];
            float s2 = g2[t] * rsqrtf(v2[t] + EPSF);
            s2ws[t] = s2;
            t2ws[t] = (b2[t]-m2[t])*s2 + be2[t];
        }
    }
}

// ---------------------------------------------------------------------------
// k1_mfma: round-6 verified compute; y stores now NON-TEMPORAL (y is
// write-once, never read -> keep it out of L2/L3 so x/w2 stay resident).
// ---------------------------------------------------------------------------
__global__ __launch_bounds__(256, 2) void k1_mfma(
    const float* __restrict__ x,
    const float* __restrict__ bd, const char* __restrict__ ws,
    const int* __restrict__ bstride, const int* __restrict__ boff,
    float* __restrict__ y)
{
    extern __shared__ char smem[];
    unsigned short* xT  = (unsigned short*)smem;            // [256][72]
    unsigned short* wdS = (unsigned short*)(smem + 36864);  // [256][72]
    float*          bdS = (float*)(smem + 73728);           // [256]

    const int t = threadIdx.x, lane = t & 63, w = t >> 6;
    const int m = lane & 15, g = lane >> 4;
    const int bid = blockIdx.x;
    const int n   = bid >> 10;
    const int row = (bid >> 1) & 511;
    const int c0  = (bid & 1) * 256;

    #pragma unroll
    for (int i = 0; i < 9; ++i)
        dma16((const char*)ws + WDWS_OFF + (t + i*256)*16,
              (char*)wdS + (t + i*256)*16);
    if (t < 64) dma16((const char*)bd + t*16, (char*)bdS + t*16);

    const size_t xbase = (size_t)n*64*HW + (size_t)row*512 + c0;
    #pragma unroll 4
    for (int jc = 0; jc < 16; ++jc) {
        int ci = w + 4*jc;
        float4 xv = *(const float4*)&x[xbase + (size_t)ci*HW + lane*4];
        xT[(lane*4+0)*72 + ci] = f2bf(xv.x);
        xT[(lane*4+1)*72 + ci] = f2bf(xv.y);
        xT[(lane*4+2)*72 + ci] = f2bf(xv.z);
        xT[(lane*4+3)*72 + ci] = f2bf(xv.w);
    }

    const int stride = bstride[0], off = boff[0];
    const bool safe = (stride == 32) && (off == 0);
    unsigned long long mv = 0;
    if (safe) {
        const unsigned char* mb = (const unsigned char*)(ws + MSKWS_OFF);
        mv = *(const unsigned long long*)&mb[n*256 + (row>>5)*16 + (bid&1)*8];
    }

    __syncthreads();

    bf16x8 bF[2][4];
    #pragma unroll
    for (int pxf = 0; pxf < 4; ++pxf)
        #pragma unroll
        for (int kk = 0; kk < 2; ++kk)
            bF[kk][pxf] = *(const bf16x8*)&xT[(w*64 + pxf*16 + m)*72 + kk*32 + g*8];

    const size_t ybase = (size_t)(n*256)*HW + (size_t)row*512 + c0;
    #pragma unroll 1
    for (int cof = 0; cof < 16; ++cof) {
        bf16x8 a0  = *(const bf16x8*)&wdS[(cof*16+m)*72 +      g*8];
        bf16x8 a1w = *(const bf16x8*)&wdS[(cof*16+m)*72 + 32 + g*8];
        f32x4 ac[4];
        #pragma unroll
        for (int pxf = 0; pxf < 4; ++pxf) {
            ac[pxf] = (f32x4){0.f,0.f,0.f,0.f};
            ac[pxf] = __builtin_amdgcn_mfma_f32_16x16x32_bf16(a0,  bF[0][pxf], ac[pxf], 0, 0, 0);
            ac[pxf] = __builtin_amdgcn_mfma_f32_16x16x32_bf16(a1w, bF[1][pxf], ac[pxf], 0, 0, 0);
        }
        #pragma unroll
        for (int pxf = 0; pxf < 4; ++pxf) {
            const int pxg = w*4 + pxf;
            const bool skip = safe && (((mv >> ((pxg>>1)*8)) & 0xffull) != 0ull);
            if (!skip) {
                #pragma unroll
                for (int j = 0; j < 4; ++j) {
                    const int co = cof*16 + g*4 + j;
                    __builtin_nontemporal_store(ac[pxf][j] + bdS[co],
                        &y[ybase + (size_t)co*HW + pxg*16 + m]);
                }
            }
        }
    }
}

// ---------------------------------------------------------------------------
// k2_fused: round-10 structure (2 WG/CU, direct w2 frags from L2, 2 bar/ch)
// + NON-TEMPORAL y stores (the R10 fix: keep the 536MB y stream out of
// L2/L3 so x and w2ws stay cache-resident; R10's 407MB HBM re-fetch gone).
// ---------------------------------------------------------------------------
__global__ __launch_bounds__(512, 4) void k2_fused(
    const float* __restrict__ x, const int* __restrict__ indices,
    const char* __restrict__ ws,
    const int* __restrict__ bstride, const int* __restrict__ boff,
    float* __restrict__ y)
{
    extern __shared__ char smem[];
    unsigned short* xT  = (unsigned short*)smem;            // [340][72] 48,960B
    unsigned short* w1s = (unsigned short*)(smem + 48960);  // [32][72]   4,608B
    unsigned short* hS  = (unsigned short*)(smem + 53568);  // [340][40] 27,200B
    // total 80,768 B  -> 2 WG/CU

    const unsigned short* w2g  = (const unsigned short*)(ws + W2WS_OFF);
    const unsigned short* w1ws = (const unsigned short*)(ws + W1WS_OFF);
    const float* t1g = (const float*)(ws + T1WS_OFF);
    const float* s2g = (const float*)(ws + S2WS_OFF);
    const float* t2g = (const float*)(ws + T2WS_OFF);

    const int t    = threadIdx.x;
    const int lane = t & 63;
    const int w    = t >> 6;
    const int m    = lane & 15;
    const int g    = lane >> 4;
    const int cog  = w >> 2;        // 0..1  co-group of 64 within this half
    const int ph   = w & 3;         // 0..3  row-pair

    const int bid = blockIdx.x;
    const int blk = bid >> 3, pz = (bid >> 1) & 3, coh = bid & 1;
    const int bn = indices[blk*3+0], gr = indices[blk*3+1], gc = indices[blk*3+2];
    const int stride = bstride[0], off = boff[0];
    const int row0 = gr*stride + off, col0 = gc*stride + off;

    // per-lane constant part of the A-frag offset (ushort units)
    const int alo = g*1024 + (cog*64 + m)*8;

    // ---- prologue: w1s(0) DMA + xT staging ----
    if (t < 288) dma16((const char*)w1ws + t*16, (char*)w1s + t*16);
    {
        const int half = lane >> 5, cc = lane & 31;
        for (int pb = w*80; pb < w*80 + 80; pb += 2) {
            int pi = pb + half;
            int r = pi >> 6, ci = pi & 63;
            int br = pz*8 + r - 1;
            if ((unsigned)br < 32u) {
                float xv = x[(size_t)bn*64*HW + (size_t)ci*HW
                             + (size_t)(row0+br)*512 + (col0+cc)];
                xT[(r*34 + cc + 1)*72 + ci] = f2bf(xv);
            }
        }
    }

    f32x4 acc[4][4];    // [cof][pxf = pr*2+chf]
    #pragma unroll
    for (int a = 0; a < 4; ++a)
        #pragma unroll
        for (int b = 0; b < 4; ++b) acc[a][b] = (f32x4){0.f,0.f,0.f,0.f};

    __syncthreads();   // xT visible, w1s(0) drained

    #pragma unroll 1
    for (int ch = 0; ch < 8; ++ch) {
        // ---- conv1 MFMA (xT, w1s) + BN1 bias from global ----
        float4 t1v0 = *(const float4*)&t1g[ch*32      + g*4];
        float4 t1v1 = *(const float4*)&t1g[ch*32 + 16 + g*4];
        f32x4 a1[3][2];
        #pragma unroll
        for (int i = 0; i < 3; ++i) {
            a1[i][0] = (f32x4){0.f,0.f,0.f,0.f};
            a1[i][1] = (f32x4){0.f,0.f,0.f,0.f};
            const int tile = w*3 + i;
            if (tile < 22) {
                #pragma unroll
                for (int kk = 0; kk < 2; ++kk) {
                    bf16x8 bF1 = *(const bf16x8*)&xT[(tile*16+m)*72 + kk*32 + g*8];
                    #pragma unroll
                    for (int hct = 0; hct < 2; ++hct) {
                        bf16x8 aF1 = *(const bf16x8*)&w1s[(hct*16+m)*72 + kk*32 + g*8];
                        a1[i][hct] = __builtin_amdgcn_mfma_f32_16x16x32_bf16(
                                         aF1, bF1, a1[i][hct], 0, 0, 0);
                    }
                }
            }
        }
        // ---- h write: bias + relu + border mask (gate p<340) ----
        #pragma unroll
        for (int i = 0; i < 3; ++i) {
            const int tile = w*3 + i;
            if (tile < 22) {
                int p = tile*16 + m;
                if (p < 340) {
                    int r = p / 34, c = p - r*34;
                    int br = pz*8 + r - 1;
                    bool valid = (c >= 1) && (c <= 32) && ((unsigned)br < 32u);
                    #pragma unroll
                    for (int hct = 0; hct < 2; ++hct) {
                        const float4 tv4 = hct ? t1v1 : t1v0;
                        unsigned short hv[4];
                        #pragma unroll
                        for (int j = 0; j < 4; ++j) {
                            float hf = fmaxf(a1[i][hct][j] +
                                             ((const float*)&tv4)[j], 0.f);
                            hv[j] = valid ? f2bf(hf) : (unsigned short)0;
                        }
                        unsigned lo = (unsigned)hv[0] | ((unsigned)hv[1] << 16);
                        unsigned hi = (unsigned)hv[2] | ((unsigned)hv[3] << 16);
                        *(uint2*)&hS[p*40 + hct*16 + g*4] = make_uint2(lo, hi);
                    }
                }
            }
        }
        __syncthreads();   // hS(ch) visible

        if (ch < 7 && t < 288)
            dma16((const char*)w1ws + (ch+1)*4608 + t*16, (char*)w1s + t*16);

        // ---- conv2: A from global (L2-resident now), B from hS ----
        __builtin_amdgcn_s_setprio(1);
        #pragma unroll
        for (int dx = 0; dx < 3; ++dx) {
            bf16x8 bFr[2][4];
            #pragma unroll
            for (int chf = 0; chf < 2; ++chf)
                #pragma unroll
                for (int ro = 0; ro < 4; ++ro)
                    bFr[chf][ro] = *(const bf16x8*)
                        &hS[((ph*2+ro)*34 + chf*16 + m + dx)*40 + g*8];
            #pragma unroll
            for (int dy = 0; dy < 3; ++dy) {
                const int abase = ((ch*2 + coh)*9 + dy*3 + dx) * 4096;
                bf16x8 aF[4];
                #pragma unroll
                for (int cof = 0; cof < 4; ++cof)
                    aF[cof] = *(const bf16x8*)&w2g[abase + alo + cof*128];
                #pragma unroll
                for (int chf = 0; chf < 2; ++chf)
                    #pragma unroll
                    for (int pr = 0; pr < 2; ++pr)
                        #pragma unroll
                        for (int cof = 0; cof < 4; ++cof)
                            acc[cof][pr*2+chf] =
                                __builtin_amdgcn_mfma_f32_16x16x32_bf16(
                                    aF[cof], bFr[chf][pr+dy],
                                    acc[cof][pr*2+chf], 0, 0, 0);
            }
        }
        __builtin_amdgcn_s_setprio(0);
        __syncthreads();   // hS readers done; w1s(ch+1) drained
    }

    // ---- epilogue: BN2 + relu + NON-TEMPORAL scatter ----
    const size_t yblk = (size_t)bn*256*HW;
    const int rbase = row0 + pz*8 + ph*2;
    #pragma unroll
    for (int cof = 0; cof < 4; ++cof) {
        const int co4 = coh*128 + cog*64 + cof*16 + g*4;
        float4 s2v = *(const float4*)&s2g[co4];
        float4 t2v = *(const float4*)&t2g[co4];
        #pragma unroll
        for (int j = 0; j < 4; ++j) {
            const int co = co4 + j;
            const float s2 = ((const float*)&s2v)[j];
            const float t2 = ((const float*)&t2v)[j];
            #pragma unroll
            for (int pxf = 0; pxf < 4; ++pxf) {
                const int rr = rbase + (pxf>>1);
                const int cc2 = col0 + (pxf&1)*16 + m;
                __builtin_nontemporal_store(
                    fmaxf(fmaf(acc[cof][pxf][j], s2, t2), 0.f),
                    &y[yblk + (size_t)co*HW + (size_t)rr*512 + cc2]);
            }
        }
    }
}

// ---------------------------------------------------------------------------
extern "C" void kernel_launch(void* const* d_in, const int* in_sizes, int n_in,
                              void* d_out, int out_size, void* d_ws, size_t ws_size,
                              hipStream_t stream) {
    const float* x       = (const float*)d_in[0];
    const int*   indices = (const int*)  d_in[2];
    const float* w1  = (const float*)d_in[3];
    const float* b1  = (const float*)d_in[4];
    const float* g1  = (const float*)d_in[5];
    const float* be1 = (const float*)d_in[6];
    const float* m1  = (const float*)d_in[7];
    const float* v1  = (const float*)d_in[8];
    const float* w2  = (const float*)d_in[9];
    const float* b2  = (const float*)d_in[10];
    const float* g2  = (const float*)d_in[11];
    const float* be2 = (const float*)d_in[12];
    const float* m2  = (const float*)d_in[13];
    const float* v2  = (const float*)d_in[14];
    const float* wd  = (const float*)d_in[21];
    const float* bd  = (const float*)d_in[22];
    const int* bstride = (const int*)d_in[24];
    const int* boff    = (const int*)d_in[25];
    float* y = (float*)d_out;
    char* ws = (char*)d_ws;

    const int nB = in_sizes[2] / 3;   // 256 blocks

    hipLaunchKernelGGL(kmask, dim3(1), dim3(512), 0, stream, indices, nB, ws);
    hipLaunchKernelGGL(kprep, dim3(2433), dim3(256), 0, stream,
                       w1, b1, g1, be1, m1, v1, w2, b2, g2, be2, m2, v2, wd, ws);
    hipLaunchKernelGGL(k1_mfma, dim3(2048), dim3(256), 74752, stream,
                       x, bd, ws, bstride, boff, y);
    hipLaunchKernelGGL(k2_fused, dim3(nB * 8), dim3(512), 80768, stream,
                       x, indices, ws, bstride, boff, y);
}